// Round 10
// baseline (662.726 us; speedup 1.0000x reference)
//
#include <hip/hip_runtime.h>

#define Nn 50000
#define Ee 600000
#define Rr 4
#define NBIN 200704             // 196*1024, padded for int4 scan
#define BN_EPS 1e-5f

typedef __bf16 bfrag  __attribute__((ext_vector_type(8)));
typedef float  f32x4  __attribute__((ext_vector_type(4)));

__device__ __forceinline__ unsigned short f2b(float f) {
    union { float f; unsigned int u; } v; v.f = f;
    return (unsigned short)((v.u + 0x7FFFu + ((v.u >> 16) & 1u)) >> 16);
}
__device__ __forceinline__ float b2f(unsigned short u) {
    union { unsigned int u; float f; } v; v.u = ((unsigned int)u) << 16; return v.f;
}

// ---- prep: xbf (blocks 0..12499) | wt (12500..13075) | hist (13076..15419) ----
__global__ __launch_bounds__(256) void prep_k(
    const float* __restrict__ x, const float* __restrict__ W1,
    const float* __restrict__ W2, const float* __restrict__ Wself,
    const int* __restrict__ ei, const int* __restrict__ et,
    unsigned int* __restrict__ xb, unsigned short* __restrict__ WT,
    int* __restrict__ hist)
{
    int b = blockIdx.x;
    if (b < 12500) {
        int i = b * 256 + threadIdx.x;
        float2 v = ((const float2*)x)[i];
        xb[i] = ((unsigned int)f2b(v.y) << 16) | f2b(v.x);
    } else if (b < 13076) {
        int idx = (b - 12500) * 256 + threadIdx.x;   // < 147456
        int mat = idx >> 14, rem = idx & 16383;
        int n = rem >> 7, k = rem & 127;
        const float* src = (mat < 4) ? (W1 + mat * 16384)
                         : (mat < 8) ? (W2 + (mat - 4) * 16384) : Wself;
        WT[idx] = f2b(src[k * 128 + n]);
    } else {
        int e = (b - 13076) * 256 + threadIdx.x;
        if (e < Ee) atomicAdd(&hist[et[e] * Nn + ei[e]], 1);
    }
}

// ---- exclusive scan over NBIN ----
__global__ __launch_bounds__(256) void scan1_k(
    const int* __restrict__ hist, int* __restrict__ offs, int* __restrict__ bsum)
{
    int t = threadIdx.x, b = blockIdx.x;
    int base = b * 1024 + t * 4;
    int4 c = *(const int4*)(hist + base);
    int s = c.x + c.y + c.z + c.w;
    __shared__ int tmp[256];
    tmp[t] = s; __syncthreads();
    for (int off = 1; off < 256; off <<= 1) {
        int v = (t >= off) ? tmp[t - off] : 0;
        __syncthreads(); tmp[t] += v; __syncthreads();
    }
    int excl = tmp[t] - s;
    int4 o; o.x = excl; o.y = excl + c.x; o.z = o.y + c.y; o.w = o.z + c.z;
    *(int4*)(offs + base) = o;
    if (t == 255) bsum[b] = tmp[255];
}
__global__ void scan2_k(const int* __restrict__ bsum, int* __restrict__ bscan)
{
    int t = threadIdx.x;
    int s = (t < 196) ? bsum[t] : 0;
    __shared__ int tmp[256];
    tmp[t] = s; __syncthreads();
    for (int off = 1; off < 256; off <<= 1) {
        int v = (t >= off) ? tmp[t - off] : 0;
        __syncthreads(); tmp[t] += v; __syncthreads();
    }
    bscan[t] = tmp[t] - s;
}
__global__ __launch_bounds__(256) void scan3_k(
    int* __restrict__ offs, int* __restrict__ cur, const int* __restrict__ bscan)
{
    int t = threadIdx.x, b = blockIdx.x;
    int add = bscan[b];
    int base = b * 1024 + t * 4;
    int4 o = *(int4*)(offs + base);
    o.x += add; o.y += add; o.z += add; o.w += add;
    *(int4*)(offs + base) = o;
    *(int4*)(cur + base) = o;
}

// ---- bucket fill: spair[pos] = (src, dst) ----
__global__ __launch_bounds__(256) void fill_k(
    const int* __restrict__ ei, const int* __restrict__ et,
    int* __restrict__ cur, int2* __restrict__ spair)
{
    int e = blockIdx.x * 256 + threadIdx.x;
    if (e >= Ee) return;
    int dst = ei[e];
    int bin = et[e] * Nn + dst;
    int pos = atomicAdd(&cur[bin], 1);
    spair[pos] = make_int2(ei[Ee + e], dst);
}

// ---- FUSED: edge-parallel agg (LDS fp32 atomics) -> @W1_r + b1 -> h1(bf16) + BN stats
//      64-row tiles, 512 threads, grid (782, 4) ----
__global__ __launch_bounds__(512) void gemm1f_k(
    const unsigned int* __restrict__ xb, const int* __restrict__ offs,
    const int2* __restrict__ spair, const unsigned short* __restrict__ WT,
    const float* __restrict__ b1, unsigned short* __restrict__ h,
    float* __restrict__ gsum, float* __restrict__ gsq)
{
    const int r  = blockIdx.y;
    const int n0 = blockIdx.x * 64;
    const int t  = threadIdx.x;

    __shared__ __attribute__((aligned(16))) float  Asf[64][130];
    __shared__ __attribute__((aligned(16))) __bf16 Ws[128][136];
    __shared__ float s_sum[128], s_sq[128];

    if (t < 128) { s_sum[t] = 0.f; s_sq[t] = 0.f; }
    const int rows = (Nn - n0 < 64) ? (Nn - n0) : 64;
    const int ebeg = offs[r * Nn + n0];
    const int eend = offs[r * Nn + n0 + rows];

    // stage W1_r (2048 uint4 / 512 thr)
    {
        const unsigned short* Wr = WT + r * 16384;
        for (int i = t; i < 2048; i += 512) {
            int n = i >> 4, kc = (i & 15) << 3;
            *(uint4*)&Ws[n][kc] = *(const uint4*)(Wr + n * 128 + kc);
        }
    }
    // base fill: Asf[row] = x[n0+row] (fp32), zeros for padded rows. 8 thr/row.
    {
        int row = t >> 3, q = t & 7;
        int gm = n0 + row;
        uint4 a = make_uint4(0,0,0,0), b = make_uint4(0,0,0,0);
        if (gm < Nn) {
            const uint4* xr = (const uint4*)(xb + (size_t)gm * 64 + q * 8);
            a = xr[0]; b = xr[1];
        }
        unsigned int uu[8] = {a.x,a.y,a.z,a.w, b.x,b.y,b.z,b.w};
        float* bas = &Asf[row][q * 16];
#pragma unroll
        for (int j = 0; j < 8; ++j) {
            bas[2*j]   = b2f((unsigned short)(uu[j] & 0xFFFF));
            bas[2*j+1] = b2f((unsigned short)(uu[j] >> 16));
        }
    }
    __syncthreads();

    // edge phase: one half-edge (128 B) per unit; uniform work, no stragglers
    {
        const int units = 2 * (eend - ebeg);
        for (int u = t; u < units; u += 512) {
            int e  = ebeg + (u >> 1);
            int hf = u & 1;
            int2 sd = spair[e];
            const uint4* p = (const uint4*)(xb + (size_t)sd.x * 64 + hf * 32);
            uint4 q0 = p[0], q1 = p[1], q2 = p[2], q3 = p[3];
            uint4 q4 = p[4], q5 = p[5], q6 = p[6], q7 = p[7];
            float* bas = &Asf[sd.y - n0][hf << 6];
            unsigned int qq[32] = {q0.x,q0.y,q0.z,q0.w, q1.x,q1.y,q1.z,q1.w,
                                   q2.x,q2.y,q2.z,q2.w, q3.x,q3.y,q3.z,q3.w,
                                   q4.x,q4.y,q4.z,q4.w, q5.x,q5.y,q5.z,q5.w,
                                   q6.x,q6.y,q6.z,q6.w, q7.x,q7.y,q7.z,q7.w};
#pragma unroll
            for (int j = 0; j < 32; ++j) {
                atomicAdd(&bas[2*j],   b2f((unsigned short)(qq[j] & 0xFFFF)));
                atomicAdd(&bas[2*j+1], b2f((unsigned short)(qq[j] >> 16)));
            }
        }
    }
    __syncthreads();

    // MFMA: 8 waves = 4 row-groups x 2 column-halves; A from fp32 LDS (cvt->bf16)
    const int w = t >> 6, l = t & 63, ln = l & 15, quad = l >> 4;
    const int rg = w & 3, ch = w >> 2;
    f32x4 acc2[4];
#pragma unroll
    for (int c = 0; c < 4; ++c) acc2[c] = (f32x4){0.f,0.f,0.f,0.f};
#pragma unroll
    for (int kk = 0; kk < 4; ++kk) {
        int ks = kk * 32 + quad * 8;
        int arow = rg * 16 + ln;
        float2 f0 = *(const float2*)&Asf[arow][ks];
        float2 f1 = *(const float2*)&Asf[arow][ks + 2];
        float2 f2 = *(const float2*)&Asf[arow][ks + 4];
        float2 f3 = *(const float2*)&Asf[arow][ks + 6];
        bfrag a;
        a[0] = (__bf16)f0.x; a[1] = (__bf16)f0.y;
        a[2] = (__bf16)f1.x; a[3] = (__bf16)f1.y;
        a[4] = (__bf16)f2.x; a[5] = (__bf16)f2.y;
        a[6] = (__bf16)f3.x; a[7] = (__bf16)f3.y;
#pragma unroll
        for (int c = 0; c < 4; ++c) {
            int col = ch * 64 + c * 16 + ln;
            bfrag b = *(const bfrag*)&Ws[col][ks];
            acc2[c] = __builtin_amdgcn_mfma_f32_16x16x32_bf16(a, b, acc2[c], 0, 0, 0);
        }
    }
    __syncthreads();    // Ws reads done; safe to reuse region

    // epilogue: +bias, BN stats (fp32), h1 bf16 into Ws-region [64][136]
    __bf16 (*Hs)[136] = (__bf16(*)[136])Ws;
#pragma unroll
    for (int c = 0; c < 4; ++c) {
        int col = ch * 64 + c * 16 + ln;
        float bias = b1[r * 128 + col];
        float ps = 0.f, pq = 0.f;
#pragma unroll
        for (int reg = 0; reg < 4; ++reg) {
            int lrow = rg * 16 + quad * 4 + reg;
            float v = acc2[c][reg] + bias;
            Hs[lrow][col] = (__bf16)v;
            if (n0 + lrow < Nn) { ps += v; pq += v * v; }
        }
        ps += __shfl_xor(ps, 16); pq += __shfl_xor(pq, 16);
        ps += __shfl_xor(ps, 32); pq += __shfl_xor(pq, 32);
        if (quad == 0) { atomicAdd(&s_sum[col], ps); atomicAdd(&s_sq[col], pq); }
    }
    __syncthreads();

    unsigned short* hr = h + (size_t)r * Nn * 128;
    for (int i = t; i < 1024; i += 512) {       // 64 rows x 16 uint4
        int m = i >> 4, kc = (i & 15) << 3;
        int gm = n0 + m;
        if (gm < Nn) *(uint4*)(hr + (size_t)gm * 128 + kc) = *(const uint4*)&Hs[m][kc];
    }
    if (t < 128) {
        atomicAdd(&gsum[r * 128 + t], s_sum[t]);
        atomicAdd(&gsq[r * 128 + t],  s_sq[t]);
    }
}

// ---- BN coefs ----
__global__ void finalize_k(
    const float* __restrict__ gsum, const float* __restrict__ gsq,
    const float* __restrict__ gamma, const float* __restrict__ beta,
    float* __restrict__ coefA, float* __restrict__ coefC)
{
    int i = threadIdx.x;   // 512
    float mean = gsum[i] * (1.0f / Nn);
    float var  = gsq[i] * (1.0f / Nn) - mean * mean;
    float a    = gamma[i] * rsqrtf(fmaxf(var, 0.f) + BN_EPS);
    coefA[i] = a;
    coefC[i] = beta[i] - mean * a;
}

// ---- out = x@W_self + sum_r relu(a*h1+c)@W2_r + biases; 128-row tiles, 512 thr ----
__global__ __launch_bounds__(512) void gemm2f_k(
    const unsigned int* __restrict__ xb,
    const unsigned short* __restrict__ h,
    const unsigned short* __restrict__ WT,
    const float* __restrict__ bself, const float* __restrict__ b2,
    const float* __restrict__ coefA, const float* __restrict__ coefC,
    float* __restrict__ out)
{
    const int n0 = blockIdx.x * 128;
    const int t  = threadIdx.x;
    __shared__ __attribute__((aligned(16))) __bf16 As[128][136];
    __shared__ __attribute__((aligned(16))) __bf16 Ws[128][136];

    const int w = t >> 6, l = t & 63, ln = l & 15, quad = l >> 4;
    f32x4 acc2[8];
#pragma unroll
    for (int c = 0; c < 8; ++c) acc2[c] = (f32x4){0.f,0.f,0.f,0.f};

    for (int rr = 0; rr < 5; ++rr) {
        const unsigned short* Wr = WT + (rr < 4 ? (4 + rr) : 8) * 16384;
        for (int i = t; i < 2048; i += 512) {
            int n = i >> 4, kc = (i & 15) << 3;
            *(uint4*)&Ws[n][kc] = *(const uint4*)(Wr + n * 128 + kc);
        }
        if (rr < 4) {
            const unsigned short* hrp = h + (size_t)rr * Nn * 128;
            const float* cA = coefA + rr * 128;
            const float* cC = coefC + rr * 128;
            for (int i = t; i < 2048; i += 512) {
                int m = i >> 4, kc = (i & 15) << 3;
                int gm = n0 + m;
                uint4 hv = make_uint4(0,0,0,0);
                if (gm < Nn) hv = *(const uint4*)(hrp + (size_t)gm * 128 + kc);
                unsigned int hu[4] = {hv.x, hv.y, hv.z, hv.w};
                unsigned int pk[4];
#pragma unroll
                for (int j = 0; j < 4; ++j) {
                    float v0 = fmaxf(cA[kc + 2*j]     * b2f((unsigned short)(hu[j] & 0xFFFF)) + cC[kc + 2*j],     0.f);
                    float v1 = fmaxf(cA[kc + 2*j + 1] * b2f((unsigned short)(hu[j] >> 16))    + cC[kc + 2*j + 1], 0.f);
                    pk[j] = ((unsigned int)f2b(v1) << 16) | f2b(v0);
                }
                *(uint4*)&As[m][kc] = make_uint4(pk[0], pk[1], pk[2], pk[3]);
            }
        } else {
            for (int i = t; i < 2048; i += 512) {
                int m = i >> 4, kc = (i & 15) << 3;
                int gm = n0 + m;
                uint4 v = make_uint4(0, 0, 0, 0);
                if (gm < Nn) v = *(const uint4*)(xb + (size_t)gm * 64 + (kc >> 1));
                *(uint4*)&As[m][kc] = v;
            }
        }
        __syncthreads();
#pragma unroll
        for (int kk = 0; kk < 4; ++kk) {
            int ks = kk * 32 + quad * 8;
            bfrag a = *(const bfrag*)&As[w * 16 + ln][ks];
#pragma unroll
            for (int c = 0; c < 8; ++c) {
                bfrag b = *(const bfrag*)&Ws[c * 16 + ln][ks];
                acc2[c] = __builtin_amdgcn_mfma_f32_16x16x32_bf16(a, b, acc2[c], 0, 0, 0);
            }
        }
        __syncthreads();
    }

    // Epilogue: fp32 transpose through Ws, coalesced stores; 2 passes of 64 rows
    float bias[8];
#pragma unroll
    for (int c = 0; c < 8; ++c) {
        int col = c * 16 + ln;
        bias[c] = bself[col] + b2[col] + b2[128 + col] + b2[256 + col] + b2[384 + col];
    }
    float* fws = (float*)Ws;
    for (int p = 0; p < 2; ++p) {
        if ((w >> 2) == p) {
#pragma unroll
            for (int c = 0; c < 8; ++c) {
                int lrow = (w & 3) * 16 + quad * 4;
                int col  = c * 16 + ln;
#pragma unroll
                for (int reg = 0; reg < 4; ++reg)
                    fws[(lrow + reg) * 132 + col] = acc2[c][reg] + bias[c];
            }
        }
        __syncthreads();
        for (int i = t; i < 2048; i += 512) {
            int m = i >> 5, kc = (i & 31) << 2;
            int gm = n0 + p * 64 + m;
            if (gm < Nn)
                *(float4*)(out + (size_t)gm * 128 + kc) = *(const float4*)&fws[m * 132 + kc];
        }
        __syncthreads();
    }
}

extern "C" void kernel_launch(void* const* d_in, const int* in_sizes, int n_in,
                              void* d_out, int out_size, void* d_ws, size_t ws_size,
                              hipStream_t stream) {
    const float* x     = (const float*)d_in[0];
    const int*   ei    = (const int*)d_in[1];
    const int*   et    = (const int*)d_in[2];
    const float* Wself = (const float*)d_in[3];
    const float* bself = (const float*)d_in[4];
    const float* W1    = (const float*)d_in[5];
    const float* b1    = (const float*)d_in[6];
    const float* gamma = (const float*)d_in[7];
    const float* beta  = (const float*)d_in[8];
    const float* W2    = (const float*)d_in[9];
    const float* b2    = (const float*)d_in[10];
    float* out = (float*)d_out;

    char* ws = (char*)d_ws;
    int*   hist  = (int*)(ws + 0);                      // 802,816
    float* gsum  = (float*)(ws + 802816);               // 2048
    float* gsq   = (float*)(ws + 804864);               // 2048
    float* coefA = (float*)(ws + 806912);               // 2048
    float* coefC = (float*)(ws + 808960);               // 2048
    int*   bsum  = (int*)(ws + 811008);                 // 1024
    int*   bscan = (int*)(ws + 812032);                 // 1024
    int*   offs  = (int*)(ws + 813056);                 // 802,816
    int*   cur   = (int*)(ws + 1615872);                // 802,816
    int2*  spair = (int2*)(ws + 2418688);               // 4,800,000
    unsigned short* h  = (unsigned short*)(ws + 7218688);   // 51,200,000
    unsigned int*   xb = (unsigned int*)(ws + 58418688);    // 12,800,000
    unsigned short* WT = (unsigned short*)(ws + 71218688);  // 294,912 -> ~71.5 MB

    (void)hipMemsetAsync(ws, 0, 806912, stream);   // hist + gsum + gsq

    const int EB = (Ee + 255) / 256;                    // 2344
    prep_k <<<12500 + 576 + EB, 256, 0, stream>>>(x, W1, W2, Wself, ei, et, xb, WT, hist);
    scan1_k<<<196, 256, 0, stream>>>(hist, offs, bsum);
    scan2_k<<<1, 256, 0, stream>>>(bsum, bscan);
    scan3_k<<<196, 256, 0, stream>>>(offs, cur, bscan);
    fill_k <<<EB, 256, 0, stream>>>(ei, et, cur, spair);

    dim3 g1((Nn + 63) / 64, Rr);        // (782, 4)
    gemm1f_k<<<g1, 512, 0, stream>>>(xb, offs, spair, WT, b1, h, gsum, gsq);
    finalize_k<<<1, 512, 0, stream>>>(gsum, gsq, gamma, beta, coefA, coefC);
    gemm2f_k<<<(Nn + 127) / 128, 512, 0, stream>>>(
        xb, h, WT, bself, b2, coefA, coefC, out);
}

// Round 11
// 269.413 us; speedup vs baseline: 2.4599x; 2.4599x over previous
//
#include <hip/hip_runtime.h>

#define Nn 50000
#define Ee 600000
#define Rr 4
#define NBIN 200704             // 196*1024, padded for int4 scan
#define BN_EPS 1e-5f
#define ECAP 2048               // LDS edge-list cap per block

typedef __bf16 bfrag  __attribute__((ext_vector_type(8)));
typedef float  f32x4  __attribute__((ext_vector_type(4)));

__device__ __forceinline__ unsigned short f2b(float f) {
    union { float f; unsigned int u; } v; v.f = f;
    return (unsigned short)((v.u + 0x7FFFu + ((v.u >> 16) & 1u)) >> 16);
}
__device__ __forceinline__ float b2f(unsigned short u) {
    union { unsigned int u; float f; } v; v.u = ((unsigned int)u) << 16; return v.f;
}

// ---- prep: xbf (blocks 0..12499) | wt (12500..13075) | hist (13076..15419) ----
__global__ __launch_bounds__(256) void prep_k(
    const float* __restrict__ x, const float* __restrict__ W1,
    const float* __restrict__ W2, const float* __restrict__ Wself,
    const int* __restrict__ ei, const int* __restrict__ et,
    unsigned int* __restrict__ xb, unsigned short* __restrict__ WT,
    int* __restrict__ hist)
{
    int b = blockIdx.x;
    if (b < 12500) {
        int i = b * 256 + threadIdx.x;
        float2 v = ((const float2*)x)[i];
        xb[i] = ((unsigned int)f2b(v.y) << 16) | f2b(v.x);
    } else if (b < 13076) {
        int idx = (b - 12500) * 256 + threadIdx.x;   // < 147456
        int mat = idx >> 14, rem = idx & 16383;
        int n = rem >> 7, k = rem & 127;
        const float* src = (mat < 4) ? (W1 + mat * 16384)
                         : (mat < 8) ? (W2 + (mat - 4) * 16384) : Wself;
        WT[idx] = f2b(src[k * 128 + n]);
    } else {
        int e = (b - 13076) * 256 + threadIdx.x;
        if (e < Ee) atomicAdd(&hist[et[e] * Nn + ei[e]], 1);
    }
}

// ---- exclusive scan over NBIN (block-local) ----
__global__ __launch_bounds__(256) void scan1_k(
    const int* __restrict__ hist, int* __restrict__ offs, int* __restrict__ bsum)
{
    int t = threadIdx.x, b = blockIdx.x;
    int base = b * 1024 + t * 4;
    int4 c = *(const int4*)(hist + base);
    int s = c.x + c.y + c.z + c.w;
    __shared__ int tmp[256];
    tmp[t] = s; __syncthreads();
    for (int off = 1; off < 256; off <<= 1) {
        int v = (t >= off) ? tmp[t - off] : 0;
        __syncthreads(); tmp[t] += v; __syncthreads();
    }
    int excl = tmp[t] - s;
    int4 o; o.x = excl; o.y = excl + c.x; o.z = o.y + c.y; o.w = o.z + c.z;
    *(int4*)(offs + base) = o;
    if (t == 255) bsum[b] = tmp[255];
}
// scan2 folded in: block b sums bsum[0..b-1] itself
__global__ __launch_bounds__(256) void scan3_k(
    int* __restrict__ offs, int* __restrict__ cur, const int* __restrict__ bsum)
{
    int t = threadIdx.x, b = blockIdx.x;
    __shared__ int tmp[256];
    tmp[t] = (t < b) ? bsum[t] : 0;       // b <= 195 < 196 entries
    __syncthreads();
    for (int off = 128; off > 0; off >>= 1) {
        if (t < off) tmp[t] += tmp[t + off];
        __syncthreads();
    }
    int add = tmp[0];
    int base = b * 1024 + t * 4;
    int4 o = *(int4*)(offs + base);
    o.x += add; o.y += add; o.z += add; o.w += add;
    *(int4*)(offs + base) = o;
    *(int4*)(cur + base) = o;
}

// ---- bucket fill ----
__global__ __launch_bounds__(256) void fill_k(
    const int* __restrict__ ei, const int* __restrict__ et,
    int* __restrict__ cur, int* __restrict__ ssrc)
{
    int e = blockIdx.x * 256 + threadIdx.x;
    if (e >= Ee) return;
    int bin = et[e] * Nn + ei[e];
    int pos = atomicAdd(&cur[bin], 1);
    ssrc[pos] = ei[Ee + e];
}

#define ACC_QUAD(u0_, u1_, u2_, u3_)                                      \
    do {                                                                  \
        unsigned int uu[16] = {u0_.x,u0_.y,u0_.z,u0_.w, u1_.x,u1_.y,u1_.z,u1_.w, \
                               u2_.x,u2_.y,u2_.z,u2_.w, u3_.x,u3_.y,u3_.z,u3_.w}; \
        _Pragma("unroll")                                                 \
        for (int jj = 0; jj < 16; ++jj) {                                 \
            acc[2*jj]   += b2f((unsigned short)(uu[jj] & 0xFFFF));        \
            acc[2*jj+1] += b2f((unsigned short)(uu[jj] >> 16));           \
        }                                                                 \
    } while (0)

// ---- FUSED: CSR gather-agg (rotated pipeline) -> @W1_r + b1 -> h1(bf16) + BN stats
//      128-row tiles, 512 threads, grid (391, 4) ----
__global__ __launch_bounds__(512) void gemm1f_k(
    const unsigned int* __restrict__ xb, const int* __restrict__ offs,
    const int* __restrict__ ssrc, const unsigned short* __restrict__ WT,
    const float* __restrict__ b1, unsigned short* __restrict__ h,
    float* __restrict__ gsum, float* __restrict__ gsq)
{
    const int r  = blockIdx.y;
    const int n0 = blockIdx.x * 128;
    const int t  = threadIdx.x;

    __shared__ __attribute__((aligned(16))) __bf16 As[128][136];
    __shared__ __attribute__((aligned(16))) __bf16 Ws[128][136];
    __shared__ float s_sum[128], s_sq[128];
    __shared__ int s_off[129];
    __shared__ int s_edge[ECAP];

    if (t < 128) { s_sum[t] = 0.f; s_sq[t] = 0.f; }
    const int rows = (Nn - n0 < 128) ? (Nn - n0) : 128;
    if (t <= rows) s_off[t] = offs[r * Nn + n0 + t];
    __syncthreads();

    const int ebeg = s_off[0];
    const int ecnt = s_off[rows] - ebeg;
    const bool inl = (ecnt <= ECAP);
    if (inl) for (int i = t; i < ecnt; i += 512) s_edge[i] = ssrc[ebeg + i];
    {
        const unsigned short* Wr = WT + r * 16384;
        for (int i = t; i < 2048; i += 512) {
            int n = i >> 4, kc = (i & 15) << 3;
            *(uint4*)&Ws[n][kc] = *(const uint4*)(Wr + n * 128 + kc);
        }
    }
    __syncthreads();

    // gather h0 = x[dst] + sum x[src]; 4 thr/row, 16 uints each;
    // rotated pipeline: edge j+1's loads issue before edge j's accumulate.
    {
        const int row = t >> 2, q = t & 3, gm = n0 + row;
        float acc[32];
#pragma unroll
        for (int j = 0; j < 32; ++j) acc[j] = 0.f;
        if (gm < Nn) {
            const uint4* xr = (const uint4*)(xb + (size_t)gm * 64 + q * 16);
            uint4 u0 = xr[0], u1 = xr[1], u2 = xr[2], u3 = xr[3];
            ACC_QUAD(u0, u1, u2, u3);
            int jb = s_off[row] - ebeg, je = s_off[row + 1] - ebeg;
            if (jb < je) {
                int s0 = inl ? s_edge[jb] : ssrc[ebeg + jb];
                const uint4* p = (const uint4*)(xb + (size_t)s0 * 64 + q * 16);
                uint4 c0 = p[0], c1 = p[1], c2 = p[2], c3 = p[3];
                for (int j = jb + 1; ; ++j) {
                    uint4 d0, d1, d2, d3;
                    const bool more = (j < je);
                    if (more) {
                        int s1 = inl ? s_edge[j] : ssrc[ebeg + j];
                        const uint4* pn = (const uint4*)(xb + (size_t)s1 * 64 + q * 16);
                        d0 = pn[0]; d1 = pn[1]; d2 = pn[2]; d3 = pn[3];
                    }
                    ACC_QUAD(c0, c1, c2, c3);
                    if (!more) break;
                    c0 = d0; c1 = d1; c2 = d2; c3 = d3;
                }
            }
        }
        unsigned int pk[16];
#pragma unroll
        for (int j = 0; j < 16; ++j)
            pk[j] = ((unsigned int)f2b(acc[2*j+1]) << 16) | f2b(acc[2*j]);
        uint4* dst = (uint4*)&As[row][q * 32];
        dst[0] = make_uint4(pk[0],  pk[1],  pk[2],  pk[3]);
        dst[1] = make_uint4(pk[4],  pk[5],  pk[6],  pk[7]);
        dst[2] = make_uint4(pk[8],  pk[9],  pk[10], pk[11]);
        dst[3] = make_uint4(pk[12], pk[13], pk[14], pk[15]);
    }
    __syncthreads();

    const int w = t >> 6, l = t & 63, ln = l & 15, quad = l >> 4;
    f32x4 acc2[8];
#pragma unroll
    for (int c = 0; c < 8; ++c) acc2[c] = (f32x4){0.f,0.f,0.f,0.f};
#pragma unroll
    for (int kk = 0; kk < 4; ++kk) {
        int ks = kk * 32 + quad * 8;
        bfrag a = *(const bfrag*)&As[w * 16 + ln][ks];
#pragma unroll
        for (int c = 0; c < 8; ++c) {
            bfrag b = *(const bfrag*)&Ws[c * 16 + ln][ks];
            acc2[c] = __builtin_amdgcn_mfma_f32_16x16x32_bf16(a, b, acc2[c], 0, 0, 0);
        }
    }
    __syncthreads();

#pragma unroll
    for (int c = 0; c < 8; ++c) {
        int col = c * 16 + ln;
        float bias = b1[r * 128 + col];
        float ps = 0.f, pq = 0.f;
#pragma unroll
        for (int reg = 0; reg < 4; ++reg) {
            int lrow = w * 16 + quad * 4 + reg;
            float v = acc2[c][reg] + bias;
            As[lrow][col] = (__bf16)v;
            if (n0 + lrow < Nn) { ps += v; pq += v * v; }
        }
        ps += __shfl_xor(ps, 16); pq += __shfl_xor(pq, 16);
        ps += __shfl_xor(ps, 32); pq += __shfl_xor(pq, 32);
        if (quad == 0) { atomicAdd(&s_sum[col], ps); atomicAdd(&s_sq[col], pq); }
    }
    __syncthreads();

    unsigned short* hr = h + (size_t)r * Nn * 128;
    for (int i = t; i < 2048; i += 512) {
        int m = i >> 4, kc = (i & 15) << 3;
        int gm = n0 + m;
        if (gm < Nn) *(uint4*)(hr + (size_t)gm * 128 + kc) = *(const uint4*)&As[m][kc];
    }
    if (t < 128) {
        atomicAdd(&gsum[r * 128 + t], s_sum[t]);
        atomicAdd(&gsq[r * 128 + t],  s_sq[t]);
    }
}

// ---- BN coefs ----
__global__ void finalize_k(
    const float* __restrict__ gsum, const float* __restrict__ gsq,
    const float* __restrict__ gamma, const float* __restrict__ beta,
    float* __restrict__ coefA, float* __restrict__ coefC)
{
    int i = threadIdx.x;   // 512
    float mean = gsum[i] * (1.0f / Nn);
    float var  = gsq[i] * (1.0f / Nn) - mean * mean;
    float a    = gamma[i] * rsqrtf(fmaxf(var, 0.f) + BN_EPS);
    coefA[i] = a;
    coefC[i] = beta[i] - mean * a;
}

// ---- out = x@W_self + sum_r relu(a*h1+c)@W2_r + biases; 128-row tiles, 512 thr ----
__global__ __launch_bounds__(512) void gemm2f_k(
    const unsigned int* __restrict__ xb,
    const unsigned short* __restrict__ h,
    const unsigned short* __restrict__ WT,
    const float* __restrict__ bself, const float* __restrict__ b2,
    const float* __restrict__ coefA, const float* __restrict__ coefC,
    float* __restrict__ out)
{
    const int n0 = blockIdx.x * 128;
    const int t  = threadIdx.x;
    __shared__ __attribute__((aligned(16))) __bf16 As[128][136];
    __shared__ __attribute__((aligned(16))) __bf16 Ws[128][136];

    const int w = t >> 6, l = t & 63, ln = l & 15, quad = l >> 4;
    f32x4 acc2[8];
#pragma unroll
    for (int c = 0; c < 8; ++c) acc2[c] = (f32x4){0.f,0.f,0.f,0.f};

    for (int rr = 0; rr < 5; ++rr) {
        const unsigned short* Wr = WT + (rr < 4 ? (4 + rr) : 8) * 16384;
        for (int i = t; i < 2048; i += 512) {
            int n = i >> 4, kc = (i & 15) << 3;
            *(uint4*)&Ws[n][kc] = *(const uint4*)(Wr + n * 128 + kc);
        }
        if (rr < 4) {
            const unsigned short* hrp = h + (size_t)rr * Nn * 128;
            const float* cA = coefA + rr * 128;
            const float* cC = coefC + rr * 128;
            for (int i = t; i < 2048; i += 512) {
                int m = i >> 4, kc = (i & 15) << 3;
                int gm = n0 + m;
                uint4 hv = make_uint4(0,0,0,0);
                if (gm < Nn) hv = *(const uint4*)(hrp + (size_t)gm * 128 + kc);
                unsigned int hu[4] = {hv.x, hv.y, hv.z, hv.w};
                unsigned int pk[4];
#pragma unroll
                for (int j = 0; j < 4; ++j) {
                    float v0 = fmaxf(cA[kc + 2*j]     * b2f((unsigned short)(hu[j] & 0xFFFF)) + cC[kc + 2*j],     0.f);
                    float v1 = fmaxf(cA[kc + 2*j + 1] * b2f((unsigned short)(hu[j] >> 16))    + cC[kc + 2*j + 1], 0.f);
                    pk[j] = ((unsigned int)f2b(v1) << 16) | f2b(v0);
                }
                *(uint4*)&As[m][kc] = make_uint4(pk[0], pk[1], pk[2], pk[3]);
            }
        } else {
            for (int i = t; i < 2048; i += 512) {
                int m = i >> 4, kc = (i & 15) << 3;
                int gm = n0 + m;
                uint4 v = make_uint4(0, 0, 0, 0);
                if (gm < Nn) v = *(const uint4*)(xb + (size_t)gm * 64 + (kc >> 1));
                *(uint4*)&As[m][kc] = v;
            }
        }
        __syncthreads();
#pragma unroll
        for (int kk = 0; kk < 4; ++kk) {
            int ks = kk * 32 + quad * 8;
            bfrag a = *(const bfrag*)&As[w * 16 + ln][ks];
#pragma unroll
            for (int c = 0; c < 8; ++c) {
                bfrag b = *(const bfrag*)&Ws[c * 16 + ln][ks];
                acc2[c] = __builtin_amdgcn_mfma_f32_16x16x32_bf16(a, b, acc2[c], 0, 0, 0);
            }
        }
        __syncthreads();
    }

    // Epilogue: fp32 transpose through Ws, coalesced stores; 2 passes of 64 rows
    float bias[8];
#pragma unroll
    for (int c = 0; c < 8; ++c) {
        int col = c * 16 + ln;
        bias[c] = bself[col] + b2[col] + b2[128 + col] + b2[256 + col] + b2[384 + col];
    }
    float* fws = (float*)Ws;
    for (int p = 0; p < 2; ++p) {
        if ((w >> 2) == p) {
#pragma unroll
            for (int c = 0; c < 8; ++c) {
                int lrow = (w & 3) * 16 + quad * 4;
                int col  = c * 16 + ln;
#pragma unroll
                for (int reg = 0; reg < 4; ++reg)
                    fws[(lrow + reg) * 132 + col] = acc2[c][reg] + bias[c];
            }
        }
        __syncthreads();
        for (int i = t; i < 2048; i += 512) {
            int m = i >> 5, kc = (i & 31) << 2;
            int gm = n0 + p * 64 + m;
            if (gm < Nn)
                *(float4*)(out + (size_t)gm * 128 + kc) = *(const float4*)&fws[m * 132 + kc];
        }
        __syncthreads();
    }
}

extern "C" void kernel_launch(void* const* d_in, const int* in_sizes, int n_in,
                              void* d_out, int out_size, void* d_ws, size_t ws_size,
                              hipStream_t stream) {
    const float* x     = (const float*)d_in[0];
    const int*   ei    = (const int*)d_in[1];
    const int*   et    = (const int*)d_in[2];
    const float* Wself = (const float*)d_in[3];
    const float* bself = (const float*)d_in[4];
    const float* W1    = (const float*)d_in[5];
    const float* b1    = (const float*)d_in[6];
    const float* gamma = (const float*)d_in[7];
    const float* beta  = (const float*)d_in[8];
    const float* W2    = (const float*)d_in[9];
    const float* b2    = (const float*)d_in[10];
    float* out = (float*)d_out;

    char* ws = (char*)d_ws;
    int*   hist  = (int*)(ws + 0);                      // 802,816
    float* gsum  = (float*)(ws + 802816);               // 2048
    float* gsq   = (float*)(ws + 804864);               // 2048
    float* coefA = (float*)(ws + 806912);               // 2048
    float* coefC = (float*)(ws + 808960);               // 2048
    int*   bsum  = (int*)(ws + 811008);                 // 1024
    int*   offs  = (int*)(ws + 813056);                 // 802,816
    int*   cur   = (int*)(ws + 1615872);                // 802,816
    int*   ssrc  = (int*)(ws + 2418688);                // 2,400,000
    unsigned short* h  = (unsigned short*)(ws + 4818688);   // 51,200,000
    unsigned int*   xb = (unsigned int*)(ws + 56018688);    // 12,800,000
    unsigned short* WT = (unsigned short*)(ws + 68818688);  // 294,912

    (void)hipMemsetAsync(ws, 0, 806912, stream);   // hist + gsum + gsq

    const int EB = (Ee + 255) / 256;                    // 2344
    prep_k <<<12500 + 576 + EB, 256, 0, stream>>>(x, W1, W2, Wself, ei, et, xb, WT, hist);
    scan1_k<<<196, 256, 0, stream>>>(hist, offs, bsum);
    scan3_k<<<196, 256, 0, stream>>>(offs, cur, bsum);
    fill_k <<<EB, 256, 0, stream>>>(ei, et, cur, ssrc);

    dim3 g1((Nn + 127) / 128, Rr);      // (391, 4)
    gemm1f_k<<<g1, 512, 0, stream>>>(xb, offs, ssrc, WT, b1, h, gsum, gsq);
    finalize_k<<<1, 512, 0, stream>>>(gsum, gsq, gamma, beta, coefA, coefC);
    gemm2f_k<<<(Nn + 127) / 128, 512, 0, stream>>>(
        xb, h, WT, bself, b2, coefA, coefC, out);
}